// Round 2
// baseline (10345.089 us; speedup 1.0000x reference)
//
#include <hip/hip_runtime.h>
#include <math.h>

#define N 64
#define NN 4096
#define SWEEPS 10

// XOR swizzle: row/column accesses both land >=2-way-free on 32 banks.
__device__ __forceinline__ int swz(int r, int c) { return r * N + (c ^ (r & 31)); }

// Tournament (round-robin) pairing: round rr in [0,63), pair j in [0,32).
// Covers every unordered pair exactly once per 63-round sweep.
__device__ __forceinline__ void pair_of(int rr, int j, int& p, int& q) {
  if (j == 0) {
    p = 63;
    q = rr;  // rr < 63
  } else {
    int a = rr + j;
    if (a >= 63) a -= 63;
    int b = rr + 63 - j;
    if (b >= 63) b -= 63;
    p = a;
    q = b;
  }
}

__global__ __launch_bounds__(256, 4) void logeig_jacobi(
    const float* __restrict__ X, float* __restrict__ out) {
  __shared__ float A[NN];
  __shared__ float V[NN];
  __shared__ float cs_[32], sn_[32];
  __shared__ float dbuf[N];

  const int tid = threadIdx.x;
  const size_t base = (size_t)blockIdx.x * NN;

  // ---- load X -> A (swizzled), V = I (swizzled) ----
  const float4* Xg = (const float4*)(X + base);
#pragma unroll
  for (int ch = 0; ch < 4; ++ch) {
    const int f = tid + 256 * ch;  // float4 index
    float4 v = Xg[f];
    const int e = f * 4;
    const int r = e >> 6, c = e & 63;
    const float vals[4] = {v.x, v.y, v.z, v.w};
#pragma unroll
    for (int m = 0; m < 4; ++m) A[swz(r, c + m)] = vals[m];
  }
#pragma unroll
  for (int j = 0; j < 16; ++j) {
    const int e = tid * 16 + j;
    const int r = e >> 6, c = e & 63;
    V[swz(r, c)] = (r == c) ? 1.0f : 0.0f;
  }
  __syncthreads();

  for (int sw = 0; sw < SWEEPS; ++sw) {
    for (int rr = 0; rr < 63; ++rr) {
      // ---- phase 1: 32 rotation angles from current diagonal 2x2 blocks ----
      if (tid < 32) {
        int p, q;
        pair_of(rr, tid, p, q);
        const float app = A[swz(p, p)];
        const float aqq = A[swz(q, q)];
        const float apq = A[swz(p, q)];
        float c = 1.0f, s = 0.0f;
        if (fabsf(apq) > 1e-37f) {  // guard: avoids 0/0 -> NaN for converged pairs
          const float tau = (aqq - app) / (2.0f * apq);
          float t = 1.0f / (fabsf(tau) + sqrtf(1.0f + tau * tau));
          t = (tau >= 0.0f) ? t : -t;
          c = 1.0f / sqrtf(1.0f + t * t);
          s = t * c;
        }
        cs_[tid] = c;
        sn_[tid] = s;
      }
      __syncthreads();

      // ---- phase 2a: A <- Q^T A Q as 1024 disjoint 2x2 block-pair updates ----
      {
        const int i = tid & 31;
        int Pi, Qi;
        pair_of(rr, i, Pi, Qi);
        const float ci = cs_[i], si = sn_[i];
#pragma unroll
        for (int m = 0; m < 4; ++m) {
          const int jj = (tid >> 5) + 8 * m;
          int pj, qj;
          pair_of(rr, jj, pj, qj);
          const float cj = cs_[jj], sj = sn_[jj];
          const float a = A[swz(Pi, pj)];
          const float b = A[swz(Pi, qj)];
          const float d = A[swz(Qi, pj)];
          const float e = A[swz(Qi, qj)];
          // right rotation (columns pj,qj)
          const float a1 = cj * a - sj * b, b1 = sj * a + cj * b;
          const float d1 = cj * d - sj * e, e1 = sj * d + cj * e;
          // left rotation (rows Pi,Qi)
          A[swz(Pi, pj)] = ci * a1 - si * d1;
          A[swz(Qi, pj)] = si * a1 + ci * d1;
          A[swz(Pi, qj)] = ci * b1 - si * e1;
          A[swz(Qi, qj)] = si * b1 + ci * e1;
        }
      }
      // ---- phase 2b: V <- V Q (column rotations; disjoint from A) ----
      {
        const int jv = tid & 31;
        int pv, qv;
        pair_of(rr, jv, pv, qv);
        const float cv = cs_[jv], sv = sn_[jv];
        const int rbase = (tid >> 5) * 8;
#pragma unroll
        for (int m = 0; m < 8; ++m) {
          const int rv = rbase + m;
          const float x = V[swz(rv, pv)];
          const float y = V[swz(rv, qv)];
          V[swz(rv, pv)] = cv * x - sv * y;
          V[swz(rv, qv)] = sv * x + cv * y;
        }
      }
      __syncthreads();
    }
  }

  // ---- eigenvalues: diagonal of (nearly) diagonalized A ----
  if (tid < 64) {
    const float lam = A[swz(tid, tid)];
    dbuf[tid] = logf(fmaxf(lam, 1e-30f));  // clamp: never NaN/inf from log
  }
  __syncthreads();

  // ---- reconstruct Y = V diag(log lam) V^T ; lane owns 4x4 tile ----
  const int r0 = (tid >> 4) << 2;
  const int c0 = (tid & 15) << 2;
  float acc[4][4] = {};
  for (int k = 0; k < N; ++k) {
    const float dk = dbuf[k];
    float vr[4], vc[4];
#pragma unroll
    for (int i2 = 0; i2 < 4; ++i2) vr[i2] = V[swz(r0 + i2, k)] * dk;
#pragma unroll
    for (int j2 = 0; j2 < 4; ++j2) vc[j2] = V[swz(c0 + j2, k)];
#pragma unroll
    for (int i2 = 0; i2 < 4; ++i2)
#pragma unroll
      for (int j2 = 0; j2 < 4; ++j2)
        acc[i2][j2] = fmaf(vr[i2], vc[j2], acc[i2][j2]);
  }

  float* Og = out + base;
#pragma unroll
  for (int i2 = 0; i2 < 4; ++i2) {
    float4 vv = {acc[i2][0], acc[i2][1], acc[i2][2], acc[i2][3]};
    *(float4*)(Og + (r0 + i2) * N + c0) = vv;
  }
}

extern "C" void kernel_launch(void* const* d_in, const int* in_sizes, int n_in,
                              void* d_out, int out_size, void* d_ws, size_t ws_size,
                              hipStream_t stream) {
  const float* X = (const float*)d_in[0];
  float* out = (float*)d_out;
  const int nmat = in_sizes[0] / NN;  // 8192
  logeig_jacobi<<<nmat, 256, 0, stream>>>(X, out);
}

// Round 3
// 8180.949 us; speedup vs baseline: 1.2645x; 1.2645x over previous
//
#include <hip/hip_runtime.h>
#include <math.h>

#define N 64
#define NN 4096
#define SWEEPS 10

// XOR swizzle: row/column accesses both land >=2-way-free on 32 banks.
__device__ __forceinline__ int swz(int r, int c) { return r * N + (c ^ (r & 31)); }

// Tournament (round-robin) pairing: round rr in [0,63), pair j in [0,32).
// Covers every unordered pair exactly once per 63-round sweep.
__device__ __forceinline__ void pair_of(int rr, int j, int& p, int& q) {
  if (j == 0) {
    p = 63;
    q = rr;  // rr < 63
  } else {
    int a = rr + j;
    if (a >= 63) a -= 63;
    int b = rr + 63 - j;
    if (b >= 63) b -= 63;
    p = a;
    q = b;
  }
}

__global__ __launch_bounds__(256, 4) void logeig_jacobi(
    const float* __restrict__ X, float* __restrict__ out) {
  __shared__ float A[NN];
  __shared__ float V[NN];
  __shared__ float cs_[32], sn_[32];
  __shared__ float dbuf[N];  // reduction scratch during sweeps; log-eigs in epilogue

  const int tid = threadIdx.x;
  const size_t base = (size_t)blockIdx.x * NN;

  // ---- load X -> A (swizzled), V = I (swizzled) ----
  const float4* Xg = (const float4*)(X + base);
#pragma unroll
  for (int ch = 0; ch < 4; ++ch) {
    const int f = tid + 256 * ch;  // float4 index
    float4 v = Xg[f];
    const int e = f * 4;
    const int r = e >> 6, c = e & 63;
    const float vals[4] = {v.x, v.y, v.z, v.w};
#pragma unroll
    for (int m = 0; m < 4; ++m) A[swz(r, c + m)] = vals[m];
  }
#pragma unroll
  for (int j = 0; j < 16; ++j) {
    const int e = tid * 16 + j;
    const int r = e >> 6, c = e & 63;
    V[swz(r, c)] = (r == c) ? 1.0f : 0.0f;
  }
  __syncthreads();

  for (int sw = 0; sw < SWEEPS; ++sw) {
    for (int rr = 0; rr < 63; ++rr) {
      // ---- phase 1: 32 rotation angles from current diagonal 2x2 blocks ----
      if (tid < 32) {
        int p, q;
        pair_of(rr, tid, p, q);
        const float app = A[swz(p, p)];
        const float aqq = A[swz(q, q)];
        const float apq = A[swz(p, q)];
        float c = 1.0f, s = 0.0f;
        if (fabsf(apq) > 1e-37f) {  // guard: avoids 0/0 -> NaN for converged pairs
          const float tau = (aqq - app) / (2.0f * apq);
          float t = 1.0f / (fabsf(tau) + sqrtf(1.0f + tau * tau));
          t = (tau >= 0.0f) ? t : -t;
          c = 1.0f / sqrtf(1.0f + t * t);
          s = t * c;
        }
        cs_[tid] = c;
        sn_[tid] = s;
      }
      __syncthreads();

      // ---- phase 2a: A <- Q^T A Q as 1024 disjoint 2x2 block-pair updates ----
      {
        const int i = tid & 31;
        int Pi, Qi;
        pair_of(rr, i, Pi, Qi);
        const float ci = cs_[i], si = sn_[i];
#pragma unroll
        for (int m = 0; m < 4; ++m) {
          const int jj = (tid >> 5) + 8 * m;
          int pj, qj;
          pair_of(rr, jj, pj, qj);
          const float cj = cs_[jj], sj = sn_[jj];
          const float a = A[swz(Pi, pj)];
          const float b = A[swz(Pi, qj)];
          const float d = A[swz(Qi, pj)];
          const float e = A[swz(Qi, qj)];
          // right rotation (columns pj,qj)
          const float a1 = cj * a - sj * b, b1 = sj * a + cj * b;
          const float d1 = cj * d - sj * e, e1 = sj * d + cj * e;
          // left rotation (rows Pi,Qi)
          A[swz(Pi, pj)] = ci * a1 - si * d1;
          A[swz(Qi, pj)] = si * a1 + ci * d1;
          A[swz(Pi, qj)] = ci * b1 - si * e1;
          A[swz(Qi, qj)] = si * b1 + ci * e1;
        }
      }
      // ---- phase 2b: V <- V Q (column rotations; disjoint from A) ----
      {
        const int jv = tid & 31;
        int pv, qv;
        pair_of(rr, jv, pv, qv);
        const float cv = cs_[jv], sv = sn_[jv];
        const int rbase = (tid >> 5) * 8;
#pragma unroll
        for (int m = 0; m < 8; ++m) {
          const int rv = rbase + m;
          const float x = V[swz(rv, pv)];
          const float y = V[swz(rv, qv)];
          V[swz(rv, pv)] = cv * x - sv * y;
          V[swz(rv, qv)] = sv * x + cv * y;
        }
      }
      __syncthreads();
    }

    // ---- convergence check: exit when off-diag is at fp32 noise level ----
    // Post-exit sweeps would only produce ~identity rotations (guarded),
    // so exiting here reproduces the full-10-sweep result to ~1e-6 rel.
    {
      float offs = 0.0f, dias = 0.0f;
#pragma unroll
      for (int j = 0; j < 16; ++j) {
        const int e = tid * 16 + j;
        const int r = e >> 6, c = e & 63;
        const float v = A[swz(r, c)];
        if (r == c) dias += v * v; else offs += v * v;
      }
#pragma unroll
      for (int o = 32; o > 0; o >>= 1) {
        offs += __shfl_down(offs, o);
        dias += __shfl_down(dias, o);
      }
      if ((tid & 63) == 0) {
        dbuf[(tid >> 6) * 2] = offs;
        dbuf[(tid >> 6) * 2 + 1] = dias;
      }
      __syncthreads();
      if (tid == 0) {
        float ofs = dbuf[0] + dbuf[2] + dbuf[4] + dbuf[6];
        float dia = dbuf[1] + dbuf[3] + dbuf[5] + dbuf[7];
        dbuf[8] = (ofs <= 1e-13f * dia) ? 1.0f : 0.0f;
      }
      __syncthreads();
      const bool done = (dbuf[8] != 0.0f);
      __syncthreads();  // flag consumed before dbuf reused / next phase1
      if (done) break;
    }
  }

  // ---- eigenvalues: diagonal of (nearly) diagonalized A ----
  if (tid < 64) {
    const float lam = A[swz(tid, tid)];
    dbuf[tid] = logf(fmaxf(lam, 1e-30f));  // clamp: never NaN/inf from log
  }
  __syncthreads();

  // ---- reconstruct Y = V diag(log lam) V^T ; lane owns 4x4 tile ----
  const int r0 = (tid >> 4) << 2;
  const int c0 = (tid & 15) << 2;
  float acc[4][4] = {};
  for (int k = 0; k < N; ++k) {
    const float dk = dbuf[k];
    float vr[4], vc[4];
#pragma unroll
    for (int i2 = 0; i2 < 4; ++i2) vr[i2] = V[swz(r0 + i2, k)] * dk;
#pragma unroll
    for (int j2 = 0; j2 < 4; ++j2) vc[j2] = V[swz(c0 + j2, k)];
#pragma unroll
    for (int i2 = 0; i2 < 4; ++i2)
#pragma unroll
      for (int j2 = 0; j2 < 4; ++j2)
        acc[i2][j2] = fmaf(vr[i2], vc[j2], acc[i2][j2]);
  }

  float* Og = out + base;
#pragma unroll
  for (int i2 = 0; i2 < 4; ++i2) {
    float4 vv = {acc[i2][0], acc[i2][1], acc[i2][2], acc[i2][3]};
    *(float4*)(Og + (r0 + i2) * N + c0) = vv;
  }
}

extern "C" void kernel_launch(void* const* d_in, const int* in_sizes, int n_in,
                              void* d_out, int out_size, void* d_ws, size_t ws_size,
                              hipStream_t stream) {
  const float* X = (const float*)d_in[0];
  float* out = (float*)d_out;
  const int nmat = in_sizes[0] / NN;  // 8192
  logeig_jacobi<<<nmat, 256, 0, stream>>>(X, out);
}